// Round 6
// baseline (1221.108 us; speedup 1.0000x reference)
//
#include <hip/hip_runtime.h>

#define N_NODES 50000
#define E_EDGES 800000
#define D_OUT   64
#define COMB    144   // 64 + 64 + 16
#define NTILES  (E_EDGES / 64)   // 12500 blocks of 64 edges

typedef float  f32x4  __attribute__((ext_vector_type(4)));
typedef __bf16 bf16x8 __attribute__((ext_vector_type(8)));
typedef __bf16 bf16x4 __attribute__((ext_vector_type(4)));

// ---------------- workspace layout (bytes) --------------------------------
#define WS_DEG     0           // int[N]      200,000
#define WS_CURSOR  200704      // int[N]      200,000
#define WS_PERM    401408      // int[E]    3,200,000
#define WS_WTS     3601408     // bf16 wts    107,520
#define WS_NUM     3708928     // f32 N*64 12,800,000
#define WS_DEN     16508928    // f32 N*8   1,600,000   (contiguous with NUM)

#define BIG_ELEMS    (64*168)   // 10752
#define SMALL_ELEMS  (64*72)    // 4608

// ---------------------------------------------------------------------------
// prep: fp32 [K][64] weights -> bf16 transposed [64][Kpad] (zero pad)
// ---------------------------------------------------------------------------
__global__ __launch_bounds__(256) void prep_kernel(
    const float* __restrict__ kW0, const float* __restrict__ kW1, const float* __restrict__ kW2,
    const float* __restrict__ vW0, const float* __restrict__ vW1, const float* __restrict__ vW2,
    const float* __restrict__ oW0, const float* __restrict__ oW1, const float* __restrict__ oW2,
    __bf16* __restrict__ wout)
{
    const int b = blockIdx.x, tid = threadIdx.x;
    const float* src;
    __bf16* dst;
    int K, Kpad, lb;
    if (b < 42)      { src = kW0; dst = wout;             K = 144; Kpad = 168; lb = b; }
    else if (b < 84) { src = vW0; dst = wout + BIG_ELEMS; K = 144; Kpad = 168; lb = b - 42; }
    else {
        const int id = (b - 84) / 18; lb = (b - 84) % 18;
        const float* s7[7] = {kW1, kW2, vW1, vW2, oW0, oW1, oW2};
        src = s7[id]; dst = wout + 2 * BIG_ELEMS + id * SMALL_ELEMS;
        K = 64; Kpad = 72;
    }
    const int idx = lb * 256 + tid;
    const int col = idx / Kpad, k = idx % Kpad;
    dst[idx] = (k < K) ? (__bf16)src[k * 64 + col] : (__bf16)0.f;
}

// ---------------------------------------------------------------------------
// sort pre-pass: degree count -> exclusive scan (cursor) -> edge-ID scatter
// ---------------------------------------------------------------------------
__global__ __launch_bounds__(256) void deg_kernel(const int* __restrict__ edge_index,
                                                  int* __restrict__ deg)
{
    const int e = blockIdx.x * 256 + threadIdx.x;
    if (e < E_EDGES) atomicAdd(&deg[edge_index[E_EDGES + e]], 1);
}

__global__ __launch_bounds__(1024) void scan_kernel(const int* __restrict__ deg,
                                                    int* __restrict__ cursor)
{
    __shared__ int wsum[16];
    __shared__ int carry_s;
    const int tid = threadIdx.x, lane = tid & 63, wv = tid >> 6;
    if (tid == 0) carry_s = 0;
    __syncthreads();
    for (int base = 0; base < N_NODES; base += 1024) {
        const int i = base + tid;
        const int v = (i < N_NODES) ? deg[i] : 0;
        int sc = v;
        #pragma unroll
        for (int off = 1; off < 64; off <<= 1) {
            int t = __shfl_up(sc, off);
            if (lane >= off) sc += t;
        }
        if (lane == 63) wsum[wv] = sc;
        const int c = carry_s;
        __syncthreads();
        if (wv == 0 && lane < 16) {
            int ws = wsum[lane];
            #pragma unroll
            for (int off = 1; off < 16; off <<= 1) {
                int t = __shfl_up(ws, off);
                if (lane >= off) ws += t;
            }
            wsum[lane] = ws;
        }
        __syncthreads();
        const int woff = (wv == 0) ? 0 : wsum[wv - 1];
        if (i < N_NODES) cursor[i] = c + woff + sc - v;
        __syncthreads();
        if (tid == 0) carry_s = c + wsum[15];
        __syncthreads();
    }
}

__global__ __launch_bounds__(256) void perm_kernel(const int* __restrict__ edge_index,
                                                   int* __restrict__ cursor,
                                                   int* __restrict__ perm)
{
    const int e = blockIdx.x * 256 + threadIdx.x;
    if (e < E_EDGES) {
        const int d = edge_index[E_EDGES + e];
        perm[atomicAdd(&cursor[d], 1)] = e;
    }
}

// ---------------------------------------------------------------------------
// MFMA fragment convention (both operands use the SAME contiguous k = hi*8+i
// placement, so any HW k-permutation cancels):
//   A: lane holds A[row=lane&15][k=(lane>>4)*8+i]
//   B: lane holds B[k=(lane>>4)*8+i][col=lane&15]  <- from Wt[col][k]
//   D: d[r] = D[row=(lane>>4)*4+r][col=lane&15]
// ---------------------------------------------------------------------------
__device__ __forceinline__ void gemm64(const __bf16* Arow, const __bf16* Wt,
                                       int hi, int row16, f32x4 acc[4])
{
    #pragma unroll
    for (int kc = 0; kc < 2; ++kc) {
        const bf16x8 a = *(const bf16x8*)(Arow + kc * 32 + hi * 8);
        #pragma unroll
        for (int n = 0; n < 4; ++n) {
            const bf16x8 bfr = *(const bf16x8*)(Wt + (n * 16 + row16) * 72 + kc * 32 + hi * 8);
            acc[n] = __builtin_amdgcn_mfma_f32_16x16x32_bf16(a, bfr, acc[n], 0, 0, 0);
        }
    }
}

__device__ __forceinline__ bf16x8 pack8(float4 a, float4 b) {
    bf16x8 r;
    r[0] = (__bf16)a.x; r[1] = (__bf16)a.y; r[2] = (__bf16)a.z; r[3] = (__bf16)a.w;
    r[4] = (__bf16)b.x; r[5] = (__bf16)b.y; r[6] = (__bf16)b.z; r[7] = (__bf16)b.w;
    return r;
}

// ===========================================================================
// Edge kernel: one wave per 16 DST-SORTED edges (via perm), zero block
// barriers. XCD-chunked bijective block swizzle keeps each dst's num/den
// lines on ONE XCD's L2 -> atomic RMWs stay local, no cross-XCD ping-pong.
// ===========================================================================
__global__ __launch_bounds__(256, 6) void edge_kernel(
    const float* __restrict__ x,
    const float* __restrict__ edge_attr,
    const int*   __restrict__ edge_index,
    const int*   __restrict__ perm,
    const float* __restrict__ q,
    const float* __restrict__ kb0, const float* __restrict__ kb1, const float* __restrict__ kb2,
    const float* __restrict__ vb0, const float* __restrict__ vb1, const float* __restrict__ vb2,
    const __bf16* __restrict__ kW0t, const __bf16* __restrict__ kW1t, const __bf16* __restrict__ kW2t,
    const __bf16* __restrict__ vW0t, const __bf16* __restrict__ vW1t, const __bf16* __restrict__ vW2t,
    float* __restrict__ num, float* __restrict__ den)
{
    __shared__ __bf16 H_s[64][72];        // wave w uses rows w*16..w*16+15 only

    const int tid   = threadIdx.x;
    const int lane  = tid & 63;
    const int w     = tid >> 6;
    const int row16 = lane & 15;
    const int hi    = lane >> 4;
    const int wrow  = w * 16;

    // bijective XCD-chunked swizzle (G=12500, 8 XCDs): q=1562, r=4
    const int xcd = blockIdx.x & 7, bi = blockIdx.x >> 3;
    const int st  = (xcd < (NTILES & 7)
                       ? xcd * ((NTILES >> 3) + 1)
                       : (NTILES & 7) * ((NTILES >> 3) + 1) + (xcd - (NTILES & 7)) * (NTILES >> 3))
                    + bi;

    const int p  = (st * 4 + w) * 16 + row16;   // sorted slot
    const int er = perm[p];                      // original edge id

    const int src  = edge_index[er];
    const int dstn = edge_index[E_EDGES + er];

    // ---- L0 A-fragments: direct register gather (k = kc*32 + hi*8 + i) ----
    bf16x8 af[5];
    {
        const float* xs = &x[(size_t)src * 64 + hi * 8];
        af[0] = pack8(*(const float4*)xs,        *(const float4*)(xs + 4));
        af[1] = pack8(*(const float4*)(xs + 32), *(const float4*)(xs + 36));
        const float* xd = &x[(size_t)dstn * 64 + hi * 8];
        af[2] = pack8(*(const float4*)xd,        *(const float4*)(xd + 4));
        af[3] = pack8(*(const float4*)(xd + 32), *(const float4*)(xd + 36));
        if (hi < 2) {
            const float* ep = &edge_attr[(size_t)er * 16 + hi * 8];
            af[4] = pack8(*(const float4*)ep, *(const float4*)(ep + 4));
        } else {
            #pragma unroll
            for (int i = 0; i < 8; ++i) af[4][i] = (__bf16)0.f;
        }
    }

    const __bf16* hrow = &H_s[wrow + row16][0];
    float ex[4][4];

    // ================= K stack =================
    {
        f32x4 acc[4] = {{0,0,0,0},{0,0,0,0},{0,0,0,0},{0,0,0,0}};
        #pragma unroll
        for (int kc = 0; kc < 5; ++kc) {
            #pragma unroll
            for (int n = 0; n < 4; ++n) {
                const bf16x8 bfr = *(const bf16x8*)(kW0t + (n * 16 + row16) * 168 + kc * 32 + hi * 8);
                acc[n] = __builtin_amdgcn_mfma_f32_16x16x32_bf16(af[kc], bfr, acc[n], 0, 0, 0);
            }
        }
        float h0[4][4];
        #pragma unroll
        for (int n = 0; n < 4; ++n) {
            const float bias = kb0[n * 16 + row16];
            #pragma unroll
            for (int r = 0; r < 4; ++r) {
                h0[n][r] = fmaxf(acc[n][r] + bias, 0.f);
                H_s[wrow + hi * 4 + r][n * 16 + row16] = (__bf16)h0[n][r];
            }
        }
        __builtin_amdgcn_wave_barrier();

        f32x4 acc1[4] = {{0,0,0,0},{0,0,0,0},{0,0,0,0},{0,0,0,0}};
        gemm64(hrow, kW1t, hi, row16, acc1);
        float h1[4][4];
        #pragma unroll
        for (int n = 0; n < 4; ++n) {
            const float bias = kb1[n * 16 + row16];
            #pragma unroll
            for (int r = 0; r < 4; ++r) {
                h1[n][r] = fmaxf(h0[n][r] + acc1[n][r] + bias, 0.f);
                H_s[wrow + hi * 4 + r][n * 16 + row16] = (__bf16)h1[n][r];
            }
        }
        __builtin_amdgcn_wave_barrier();

        f32x4 acc2[4] = {{0,0,0,0},{0,0,0,0},{0,0,0,0},{0,0,0,0}};
        gemm64(hrow, kW2t, hi, row16, acc2);

        #pragma unroll
        for (int n = 0; n < 4; ++n) {
            const float bias = kb2[n * 16 + row16];
            const float qv   = q[n * 16 + row16];
            #pragma unroll
            for (int r = 0; r < 4; ++r) {
                const float kk = h1[n][r] + acc2[n][r] + bias;
                float p2 = qv * kk;
                p2 += __shfl_xor(p2, 1);
                p2 += __shfl_xor(p2, 2);
                p2 += __shfl_xor(p2, 4);
                ex[n][r] = __expf(p2 * 0.35355339059327373f); // shift-free softmax: scores O(1)
            }
        }
    }

    // ================= V stack (af reused) =================
    float vv[4][4];
    {
        f32x4 acc[4] = {{0,0,0,0},{0,0,0,0},{0,0,0,0},{0,0,0,0}};
        #pragma unroll
        for (int kc = 0; kc < 5; ++kc) {
            #pragma unroll
            for (int n = 0; n < 4; ++n) {
                const bf16x8 bfr = *(const bf16x8*)(vW0t + (n * 16 + row16) * 168 + kc * 32 + hi * 8);
                acc[n] = __builtin_amdgcn_mfma_f32_16x16x32_bf16(af[kc], bfr, acc[n], 0, 0, 0);
            }
        }
        float h0[4][4];
        #pragma unroll
        for (int n = 0; n < 4; ++n) {
            const float bias = vb0[n * 16 + row16];
            #pragma unroll
            for (int r = 0; r < 4; ++r) {
                h0[n][r] = fmaxf(acc[n][r] + bias, 0.f);
                H_s[wrow + hi * 4 + r][n * 16 + row16] = (__bf16)h0[n][r];
            }
        }
        __builtin_amdgcn_wave_barrier();

        f32x4 acc1[4] = {{0,0,0,0},{0,0,0,0},{0,0,0,0},{0,0,0,0}};
        gemm64(hrow, vW1t, hi, row16, acc1);
        float h1[4][4];
        #pragma unroll
        for (int n = 0; n < 4; ++n) {
            const float bias = vb1[n * 16 + row16];
            #pragma unroll
            for (int r = 0; r < 4; ++r) {
                h1[n][r] = fmaxf(h0[n][r] + acc1[n][r] + bias, 0.f);
                H_s[wrow + hi * 4 + r][n * 16 + row16] = (__bf16)h1[n][r];
            }
        }
        __builtin_amdgcn_wave_barrier();

        f32x4 acc2[4] = {{0,0,0,0},{0,0,0,0},{0,0,0,0},{0,0,0,0}};
        gemm64(hrow, vW2t, hi, row16, acc2);
        #pragma unroll
        for (int n = 0; n < 4; ++n) {
            const float bias = vb2[n * 16 + row16];
            #pragma unroll
            for (int r = 0; r < 4; ++r)
                vv[n][r] = h1[n][r] + acc2[n][r] + bias;
        }
    }

    // ====== atomic scatter: dst-sorted + XCD-chunked -> L2-local RMW ======
    const int b3 = row16 >> 3;
    #pragma unroll
    for (int r = 0; r < 4; ++r) {
        const int drow = __shfl(dstn, hi * 4 + r);
        if ((lane & 7) == 0) {
            #pragma unroll
            for (int n = 0; n < 4; ++n)
                atomicAdd(&den[(size_t)drow * 8 + 2 * n + b3], ex[n][r]);
        }
        #pragma unroll
        for (int n = 0; n < 4; ++n)
            atomicAdd(&num[(size_t)drow * 64 + n * 16 + row16], ex[n][r] * vv[n][r]);
    }
}

// ---------------------------------------------------------------------------
// Node kernel: block = 64 nodes; aggr = relu(num/den) -> out stack -> skip.
// ---------------------------------------------------------------------------
__global__ __launch_bounds__(256) void node_kernel(
    const float* __restrict__ x,
    const float* __restrict__ num, const float* __restrict__ den,
    const float* __restrict__ ob0, const float* __restrict__ ob1, const float* __restrict__ ob2,
    const __bf16* __restrict__ oW0t, const __bf16* __restrict__ oW1t, const __bf16* __restrict__ oW2t,
    float* __restrict__ out)
{
    __shared__ __bf16 A_s[64][72];
    __shared__ __bf16 H_s[64][72];

    const int tid  = threadIdx.x;
    const int lane = tid & 63;
    const int w    = tid >> 6;
    const int n0   = blockIdx.x * 64;
    const int row16 = lane & 15;
    const int hi    = lane >> 4;

    for (int i = tid; i < 64 * 16; i += 256) {
        const int r = i >> 4, cc = (i & 15) * 4;
        const int node = n0 + r;
        bf16x4 h; h[0] = h[1] = h[2] = h[3] = (__bf16)0.f;
        if (node < N_NODES) {
            const float dh = den[(size_t)node * 8 + (cc >> 3)];
            if (dh > 0.f) {
                const float4 f = *(const float4*)&num[(size_t)node * 64 + cc];
                const float inv = 1.f / dh;
                h[0] = (__bf16)fmaxf(f.x * inv, 0.f);
                h[1] = (__bf16)fmaxf(f.y * inv, 0.f);
                h[2] = (__bf16)fmaxf(f.z * inv, 0.f);
                h[3] = (__bf16)fmaxf(f.w * inv, 0.f);
            }
        }
        *(bf16x4*)&A_s[r][cc] = h;
    }
    __syncthreads();

    const __bf16* arow = &A_s[w * 16 + row16][0];
    const __bf16* hrow = &H_s[w * 16 + row16][0];

    f32x4 acc[4] = {{0,0,0,0},{0,0,0,0},{0,0,0,0},{0,0,0,0}};
    gemm64(arow, oW0t, hi, row16, acc);
    float h0[4][4];
    #pragma unroll
    for (int n = 0; n < 4; ++n) {
        const float bias = ob0[n * 16 + row16];
        #pragma unroll
        for (int r = 0; r < 4; ++r) {
            h0[n][r] = fmaxf(acc[n][r] + bias, 0.f);
            H_s[w * 16 + hi * 4 + r][n * 16 + row16] = (__bf16)h0[n][r];
        }
    }
    __builtin_amdgcn_wave_barrier();

    f32x4 acc1[4] = {{0,0,0,0},{0,0,0,0},{0,0,0,0},{0,0,0,0}};
    gemm64(hrow, oW1t, hi, row16, acc1);
    float h1[4][4];
    #pragma unroll
    for (int n = 0; n < 4; ++n) {
        const float bias = ob1[n * 16 + row16];
        #pragma unroll
        for (int r = 0; r < 4; ++r) {
            h1[n][r] = fmaxf(h0[n][r] + acc1[n][r] + bias, 0.f);
            H_s[w * 16 + hi * 4 + r][n * 16 + row16] = (__bf16)h1[n][r];
        }
    }
    __builtin_amdgcn_wave_barrier();

    f32x4 acc2[4] = {{0,0,0,0},{0,0,0,0},{0,0,0,0},{0,0,0,0}};
    gemm64(hrow, oW2t, hi, row16, acc2);
    #pragma unroll
    for (int n = 0; n < 4; ++n) {
        const float bias = ob2[n * 16 + row16];
        #pragma unroll
        for (int r = 0; r < 4; ++r) {
            const int node = n0 + w * 16 + hi * 4 + r;
            if (node < N_NODES) {
                const int col = n * 16 + row16;
                const float o = h1[n][r] + acc2[n][r] + bias;
                out[(size_t)node * 64 + col] = fmaxf(x[(size_t)node * 64 + col] + o, 0.f);
            }
        }
    }
}

extern "C" void kernel_launch(void* const* d_in, const int* in_sizes, int n_in,
                              void* d_out, int out_size, void* d_ws, size_t ws_size,
                              hipStream_t stream) {
    const float* x  = (const float*)d_in[0];
    const float* ea = (const float*)d_in[1];
    const int*   ei = (const int*)d_in[2];
    const float* q  = (const float*)d_in[3];
    const float* kW0 = (const float*)d_in[4];  const float* kb0 = (const float*)d_in[5];
    const float* kW1 = (const float*)d_in[6];  const float* kb1 = (const float*)d_in[7];
    const float* kW2 = (const float*)d_in[8];  const float* kb2 = (const float*)d_in[9];
    const float* vW0 = (const float*)d_in[10]; const float* vb0 = (const float*)d_in[11];
    const float* vW1 = (const float*)d_in[12]; const float* vb1 = (const float*)d_in[13];
    const float* vW2 = (const float*)d_in[14]; const float* vb2 = (const float*)d_in[15];
    const float* oW0 = (const float*)d_in[16]; const float* ob0 = (const float*)d_in[17];
    const float* oW1 = (const float*)d_in[18]; const float* ob1 = (const float*)d_in[19];
    const float* oW2 = (const float*)d_in[20]; const float* ob2 = (const float*)d_in[21];

    char* ws = (char*)d_ws;
    int*    deg    = (int*)(ws + WS_DEG);
    int*    cursor = (int*)(ws + WS_CURSOR);
    int*    perm   = (int*)(ws + WS_PERM);
    __bf16* wts    = (__bf16*)(ws + WS_WTS);
    float*  num    = (float*)(ws + WS_NUM);
    float*  den    = (float*)(ws + WS_DEN);

    __bf16* kW0t = wts;
    __bf16* vW0t = wts + BIG_ELEMS;
    __bf16* sm   = wts + 2 * BIG_ELEMS;
    __bf16* kW1t = sm;                   __bf16* kW2t = sm + SMALL_ELEMS;
    __bf16* vW1t = sm + 2 * SMALL_ELEMS; __bf16* vW2t = sm + 3 * SMALL_ELEMS;
    __bf16* oW0t = sm + 4 * SMALL_ELEMS; __bf16* oW1t = sm + 5 * SMALL_ELEMS;
    __bf16* oW2t = sm + 6 * SMALL_ELEMS;

    // zero degree counters and num/den accumulators (NUM/DEN contiguous)
    hipMemsetAsync(deg, 0, (size_t)N_NODES * sizeof(int), stream);
    hipMemsetAsync(num, 0, (size_t)N_NODES * (64 + 8) * sizeof(float), stream);

    // sort pre-pass: deg -> scan(cursor) -> perm (edge IDs sorted by dst)
    deg_kernel<<<E_EDGES / 256, 256, 0, stream>>>(ei, deg);
    scan_kernel<<<1, 1024, 0, stream>>>(deg, cursor);
    perm_kernel<<<E_EDGES / 256, 256, 0, stream>>>(ei, cursor, perm);

    prep_kernel<<<210, 256, 0, stream>>>(kW0, kW1, kW2, vW0, vW1, vW2, oW0, oW1, oW2, wts);

    edge_kernel<<<NTILES, 256, 0, stream>>>(
        x, ea, ei, perm, q,
        kb0, kb1, kb2, vb0, vb1, vb2,
        kW0t, kW1t, kW2t, vW0t, vW1t, vW2t,
        num, den);

    node_kernel<<<(N_NODES + 63) / 64, 256, 0, stream>>>(
        x, num, den, ob0, ob1, ob2, oW0t, oW1t, oW2t, (float*)d_out);
}

// Round 7
// 523.084 us; speedup vs baseline: 2.3344x; 2.3344x over previous
//
#include <hip/hip_runtime.h>

#define N_NODES 50000
#define E_EDGES 800000
#define D_OUT   64
#define COMB    144   // 64 + 64 + 16

typedef float  f32x4  __attribute__((ext_vector_type(4)));
typedef __bf16 bf16x8 __attribute__((ext_vector_type(8)));
typedef __bf16 bf16x4 __attribute__((ext_vector_type(4)));

// ---------------- workspace layout (bytes, 256-aligned) -------------------
#define WS_DEG     0           // int[N]       200,000
#define WS_START   200704      // int[N]       200,000
#define WS_CURSOR  401408      // int[N]       200,000
#define WS_WTS     602112      // bf16 wts     107,520
#define WS_PERM    709888      // int[E]     3,200,000
#define WS_MSG     3909888     // bf16[E][72] 115,200,000  (end 119.1MB)

#define BIG_ELEMS    (64*168)   // 10752
#define SMALL_ELEMS  (64*72)    // 4608

// ---------------------------------------------------------------------------
// prep: fp32 [K][64] weights -> bf16 transposed [64][Kpad] (zero pad)
// ---------------------------------------------------------------------------
__global__ __launch_bounds__(256) void prep_kernel(
    const float* __restrict__ kW0, const float* __restrict__ kW1, const float* __restrict__ kW2,
    const float* __restrict__ vW0, const float* __restrict__ vW1, const float* __restrict__ vW2,
    const float* __restrict__ oW0, const float* __restrict__ oW1, const float* __restrict__ oW2,
    __bf16* __restrict__ wout)
{
    const int b = blockIdx.x, tid = threadIdx.x;
    const float* src;
    __bf16* dst;
    int K, Kpad, lb;
    if (b < 42)      { src = kW0; dst = wout;             K = 144; Kpad = 168; lb = b; }
    else if (b < 84) { src = vW0; dst = wout + BIG_ELEMS; K = 144; Kpad = 168; lb = b - 42; }
    else {
        const int id = (b - 84) / 18; lb = (b - 84) % 18;
        const float* s7[7] = {kW1, kW2, vW1, vW2, oW0, oW1, oW2};
        src = s7[id]; dst = wout + 2 * BIG_ELEMS + id * SMALL_ELEMS;
        K = 64; Kpad = 72;
    }
    const int idx = lb * 256 + tid;
    const int col = idx / Kpad, k = idx % Kpad;
    dst[idx] = (k < K) ? (__bf16)src[k * 64 + col] : (__bf16)0.f;
}

// ---------------------------------------------------------------------------
// CSR pre-pass (needed only by aggr): degree -> scan(start,cursor) -> perm
// ---------------------------------------------------------------------------
__global__ __launch_bounds__(256) void deg_kernel(const int* __restrict__ edge_index,
                                                  int* __restrict__ deg)
{
    const int e = blockIdx.x * 256 + threadIdx.x;
    if (e < E_EDGES) atomicAdd(&deg[edge_index[E_EDGES + e]], 1);
}

__global__ __launch_bounds__(1024) void scan_kernel(const int* __restrict__ deg,
                                                    int* __restrict__ start,
                                                    int* __restrict__ cursor)
{
    __shared__ int wsum[16];
    __shared__ int carry_s;
    const int tid = threadIdx.x, lane = tid & 63, wv = tid >> 6;
    if (tid == 0) carry_s = 0;
    __syncthreads();
    for (int base = 0; base < N_NODES; base += 1024) {
        const int i = base + tid;
        const int v = (i < N_NODES) ? deg[i] : 0;
        int sc = v;
        #pragma unroll
        for (int off = 1; off < 64; off <<= 1) {
            int t = __shfl_up(sc, off);
            if (lane >= off) sc += t;
        }
        if (lane == 63) wsum[wv] = sc;
        const int c = carry_s;
        __syncthreads();
        if (wv == 0 && lane < 16) {
            int ws = wsum[lane];
            #pragma unroll
            for (int off = 1; off < 16; off <<= 1) {
                int t = __shfl_up(ws, off);
                if (lane >= off) ws += t;
            }
            wsum[lane] = ws;
        }
        __syncthreads();
        const int woff = (wv == 0) ? 0 : wsum[wv - 1];
        const int excl = c + woff + sc - v;
        if (i < N_NODES) { start[i] = excl; cursor[i] = excl; }
        __syncthreads();
        if (tid == 0) carry_s = c + wsum[15];
        __syncthreads();
    }
}

__global__ __launch_bounds__(256) void perm_kernel(const int* __restrict__ edge_index,
                                                   int* __restrict__ cursor,
                                                   int* __restrict__ perm)
{
    const int e = blockIdx.x * 256 + threadIdx.x;
    if (e < E_EDGES) {
        const int d = edge_index[E_EDGES + e];
        perm[atomicAdd(&cursor[d], 1)] = e;
    }
}

// ---------------------------------------------------------------------------
// MFMA fragment convention (both operands use the SAME contiguous k = hi*8+i
// placement, so any HW k-permutation cancels):
//   A: lane holds A[row=lane&15][k=(lane>>4)*8+i]
//   B: lane holds B[k=(lane>>4)*8+i][col=lane&15]  <- from Wt[col][k]
//   D: d[r] = D[row=(lane>>4)*4+r][col=lane&15]
// ---------------------------------------------------------------------------
__device__ __forceinline__ void gemm64(const __bf16* Arow, const __bf16* Wt,
                                       int hi, int row16, f32x4 acc[4])
{
    #pragma unroll
    for (int kc = 0; kc < 2; ++kc) {
        const bf16x8 a = *(const bf16x8*)(Arow + kc * 32 + hi * 8);
        #pragma unroll
        for (int n = 0; n < 4; ++n) {
            const bf16x8 bfr = *(const bf16x8*)(Wt + (n * 16 + row16) * 72 + kc * 32 + hi * 8);
            acc[n] = __builtin_amdgcn_mfma_f32_16x16x32_bf16(a, bfr, acc[n], 0, 0, 0);
        }
    }
}

__device__ __forceinline__ bf16x8 pack8(float4 a, float4 b) {
    bf16x8 r;
    r[0] = (__bf16)a.x; r[1] = (__bf16)a.y; r[2] = (__bf16)a.z; r[3] = (__bf16)a.w;
    r[4] = (__bf16)b.x; r[5] = (__bf16)b.y; r[6] = (__bf16)b.z; r[7] = (__bf16)b.w;
    return r;
}

// ===========================================================================
// Edge kernel: one wave per 16 edges in NATURAL order, zero barriers, ZERO
// atomics. Writes message row  msg[e] = [ex*v (64 bf16) | ex (8 bf16)]  at
// the edge's natural slot -> perfectly sequential streaming stores.
// ===========================================================================
__global__ __launch_bounds__(256, 6) void edge_kernel(
    const float* __restrict__ x,
    const float* __restrict__ edge_attr,
    const int*   __restrict__ edge_index,
    const float* __restrict__ q,
    const float* __restrict__ kb0, const float* __restrict__ kb1, const float* __restrict__ kb2,
    const float* __restrict__ vb0, const float* __restrict__ vb1, const float* __restrict__ vb2,
    const __bf16* __restrict__ kW0t, const __bf16* __restrict__ kW1t, const __bf16* __restrict__ kW2t,
    const __bf16* __restrict__ vW0t, const __bf16* __restrict__ vW1t, const __bf16* __restrict__ vW2t,
    __bf16* __restrict__ msg)
{
    __shared__ __bf16 H_s[64][72];        // wave w uses rows w*16..w*16+15 only

    const int tid   = threadIdx.x;
    const int lane  = tid & 63;
    const int w     = tid >> 6;
    const int row16 = lane & 15;
    const int hi    = lane >> 4;
    const int wrow  = w * 16;

    const int e0 = (blockIdx.x * 4 + w) * 16;   // wave's 16 edges
    const int er = e0 + row16;                  // this lane's A-row edge

    const int src  = edge_index[er];
    const int dstn = edge_index[E_EDGES + er];

    // ---- L0 A-fragments: direct register gather (k = kc*32 + hi*8 + i) ----
    bf16x8 af[5];
    {
        const float* xs = &x[(size_t)src * 64 + hi * 8];
        af[0] = pack8(*(const float4*)xs,        *(const float4*)(xs + 4));
        af[1] = pack8(*(const float4*)(xs + 32), *(const float4*)(xs + 36));
        const float* xd = &x[(size_t)dstn * 64 + hi * 8];
        af[2] = pack8(*(const float4*)xd,        *(const float4*)(xd + 4));
        af[3] = pack8(*(const float4*)(xd + 32), *(const float4*)(xd + 36));
        if (hi < 2) {
            const float* ep = &edge_attr[(size_t)er * 16 + hi * 8];
            af[4] = pack8(*(const float4*)ep, *(const float4*)(ep + 4));
        } else {
            #pragma unroll
            for (int i = 0; i < 8; ++i) af[4][i] = (__bf16)0.f;
        }
    }

    const __bf16* hrow = &H_s[wrow + row16][0];
    float ex[4][4];

    // ================= K stack =================
    {
        f32x4 acc[4] = {{0,0,0,0},{0,0,0,0},{0,0,0,0},{0,0,0,0}};
        #pragma unroll
        for (int kc = 0; kc < 5; ++kc) {
            #pragma unroll
            for (int n = 0; n < 4; ++n) {
                const bf16x8 bfr = *(const bf16x8*)(kW0t + (n * 16 + row16) * 168 + kc * 32 + hi * 8);
                acc[n] = __builtin_amdgcn_mfma_f32_16x16x32_bf16(af[kc], bfr, acc[n], 0, 0, 0);
            }
        }
        float h0[4][4];
        #pragma unroll
        for (int n = 0; n < 4; ++n) {
            const float bias = kb0[n * 16 + row16];
            #pragma unroll
            for (int r = 0; r < 4; ++r) {
                h0[n][r] = fmaxf(acc[n][r] + bias, 0.f);
                H_s[wrow + hi * 4 + r][n * 16 + row16] = (__bf16)h0[n][r];
            }
        }
        __builtin_amdgcn_wave_barrier();

        f32x4 acc1[4] = {{0,0,0,0},{0,0,0,0},{0,0,0,0},{0,0,0,0}};
        gemm64(hrow, kW1t, hi, row16, acc1);
        float h1[4][4];
        #pragma unroll
        for (int n = 0; n < 4; ++n) {
            const float bias = kb1[n * 16 + row16];
            #pragma unroll
            for (int r = 0; r < 4; ++r) {
                h1[n][r] = fmaxf(h0[n][r] + acc1[n][r] + bias, 0.f);
                H_s[wrow + hi * 4 + r][n * 16 + row16] = (__bf16)h1[n][r];
            }
        }
        __builtin_amdgcn_wave_barrier();

        f32x4 acc2[4] = {{0,0,0,0},{0,0,0,0},{0,0,0,0},{0,0,0,0}};
        gemm64(hrow, kW2t, hi, row16, acc2);

        // scores: head = 2n + (row16>>3)
        #pragma unroll
        for (int n = 0; n < 4; ++n) {
            const float bias = kb2[n * 16 + row16];
            const float qv   = q[n * 16 + row16];
            #pragma unroll
            for (int r = 0; r < 4; ++r) {
                const float kk = h1[n][r] + acc2[n][r] + bias;
                float p2 = qv * kk;
                p2 += __shfl_xor(p2, 1);
                p2 += __shfl_xor(p2, 2);
                p2 += __shfl_xor(p2, 4);
                ex[n][r] = __expf(p2 * 0.35355339059327373f); // shift-free softmax: scores O(1)
            }
        }
    }

    // ================= V stack (af reused) =================
    float vv[4][4];
    {
        f32x4 acc[4] = {{0,0,0,0},{0,0,0,0},{0,0,0,0},{0,0,0,0}};
        #pragma unroll
        for (int kc = 0; kc < 5; ++kc) {
            #pragma unroll
            for (int n = 0; n < 4; ++n) {
                const bf16x8 bfr = *(const bf16x8*)(vW0t + (n * 16 + row16) * 168 + kc * 32 + hi * 8);
                acc[n] = __builtin_amdgcn_mfma_f32_16x16x32_bf16(af[kc], bfr, acc[n], 0, 0, 0);
            }
        }
        float h0[4][4];
        #pragma unroll
        for (int n = 0; n < 4; ++n) {
            const float bias = vb0[n * 16 + row16];
            #pragma unroll
            for (int r = 0; r < 4; ++r) {
                h0[n][r] = fmaxf(acc[n][r] + bias, 0.f);
                H_s[wrow + hi * 4 + r][n * 16 + row16] = (__bf16)h0[n][r];
            }
        }
        __builtin_amdgcn_wave_barrier();

        f32x4 acc1[4] = {{0,0,0,0},{0,0,0,0},{0,0,0,0},{0,0,0,0}};
        gemm64(hrow, vW1t, hi, row16, acc1);
        float h1[4][4];
        #pragma unroll
        for (int n = 0; n < 4; ++n) {
            const float bias = vb1[n * 16 + row16];
            #pragma unroll
            for (int r = 0; r < 4; ++r) {
                h1[n][r] = fmaxf(h0[n][r] + acc1[n][r] + bias, 0.f);
                H_s[wrow + hi * 4 + r][n * 16 + row16] = (__bf16)h1[n][r];
            }
        }
        __builtin_amdgcn_wave_barrier();

        f32x4 acc2[4] = {{0,0,0,0},{0,0,0,0},{0,0,0,0},{0,0,0,0}};
        gemm64(hrow, vW2t, hi, row16, acc2);
        #pragma unroll
        for (int n = 0; n < 4; ++n) {
            const float bias = vb2[n * 16 + row16];
            #pragma unroll
            for (int r = 0; r < 4; ++r)
                vv[n][r] = h1[n][r] + acc2[n][r] + bias;
        }
    }

    // ====== message store: natural slot = edge id, sequential, no RMW ======
    #pragma unroll
    for (int r = 0; r < 4; ++r) {
        __bf16* mrow = msg + (size_t)(e0 + hi * 4 + r) * 72;
        #pragma unroll
        for (int n = 0; n < 4; ++n)
            mrow[n * 16 + row16] = (__bf16)(ex[n][r] * vv[n][r]);
        if ((row16 & 7) == 0) {                      // row16 in {0,8}
            #pragma unroll
            for (int n = 0; n < 4; ++n)
                mrow[64 + 2 * n + (row16 >> 3)] = (__bf16)ex[n][r];
        }
    }
}

// ---------------------------------------------------------------------------
// Aggregation: one wave per node; gathers its CSR slot range via perm,
// fp32-accumulates, writes relu(num/den) as f32 into d_out (scratch).
// ---------------------------------------------------------------------------
__global__ __launch_bounds__(256, 8) void aggr_kernel(
    const int* __restrict__ start, const int* __restrict__ endc,
    const int* __restrict__ perm, const __bf16* __restrict__ msg,
    float* __restrict__ aggr_out)
{
    const int lane = threadIdx.x & 63;
    const int n    = blockIdx.x * 4 + (threadIdx.x >> 6);
    if (n >= N_NODES) return;
    int s = start[n];
    const int e = endc[n];            // cursor after perm == start[n+1]
    float accm = 0.f, acce = 0.f;
    for (; s + 1 < e; s += 2) {
        const int p0 = perm[s], p1 = perm[s + 1];
        const size_t b0 = (size_t)p0 * 72, b1 = (size_t)p1 * 72;
        const float m0 = (float)msg[b0 + lane];
        const float e0 = (float)msg[b0 + 64 + (lane >> 3)];
        const float m1 = (float)msg[b1 + lane];
        const float e1 = (float)msg[b1 + 64 + (lane >> 3)];
        accm += m0 + m1; acce += e0 + e1;
    }
    if (s < e) {
        const size_t b0 = (size_t)perm[s] * 72;
        accm += (float)msg[b0 + lane];
        acce += (float)msg[b0 + 64 + (lane >> 3)];
    }
    const float a = (acce > 0.f) ? fmaxf(accm / acce, 0.f) : 0.f;
    aggr_out[(size_t)n * 64 + lane] = a;
}

// ---------------------------------------------------------------------------
// Node kernel: stages f32 aggr (from d_out scratch) into LDS, runs out
// stack, overwrites d_out with the final result. Per-block read==write rows.
// ---------------------------------------------------------------------------
__global__ __launch_bounds__(256) void node_kernel(
    const float* __restrict__ x, const float* __restrict__ aggr_in,
    const float* __restrict__ ob0, const float* __restrict__ ob1, const float* __restrict__ ob2,
    const __bf16* __restrict__ oW0t, const __bf16* __restrict__ oW1t, const __bf16* __restrict__ oW2t,
    float* __restrict__ out)
{
    __shared__ __bf16 A_s[64][72];
    __shared__ __bf16 H_s[64][72];

    const int tid  = threadIdx.x;
    const int lane = tid & 63;
    const int w    = tid >> 6;
    const int n0   = blockIdx.x * 64;
    const int row16 = lane & 15;
    const int hi    = lane >> 4;

    {   // stage aggr rows (f32 -> bf16)
        const int r = tid >> 2, seg = tid & 3;       // 64 rows x 4 segs x 16
        const int node = n0 + r;
        #pragma unroll
        for (int g = 0; g < 4; ++g) {
            bf16x4 h; h[0] = h[1] = h[2] = h[3] = (__bf16)0.f;
            if (node < N_NODES) {
                const float4 f = *(const float4*)&aggr_in[(size_t)node * 64 + seg * 16 + g * 4];
                h[0] = (__bf16)f.x; h[1] = (__bf16)f.y; h[2] = (__bf16)f.z; h[3] = (__bf16)f.w;
            }
            *(bf16x4*)&A_s[r][seg * 16 + g * 4] = h;
        }
    }
    __syncthreads();

    const __bf16* arow = &A_s[w * 16 + row16][0];
    const __bf16* hrow = &H_s[w * 16 + row16][0];

    f32x4 acc[4] = {{0,0,0,0},{0,0,0,0},{0,0,0,0},{0,0,0,0}};
    gemm64(arow, oW0t, hi, row16, acc);
    float h0[4][4];
    #pragma unroll
    for (int n = 0; n < 4; ++n) {
        const float bias = ob0[n * 16 + row16];
        #pragma unroll
        for (int r = 0; r < 4; ++r) {
            h0[n][r] = fmaxf(acc[n][r] + bias, 0.f);
            H_s[w * 16 + hi * 4 + r][n * 16 + row16] = (__bf16)h0[n][r];
        }
    }
    __builtin_amdgcn_wave_barrier();

    f32x4 acc1[4] = {{0,0,0,0},{0,0,0,0},{0,0,0,0},{0,0,0,0}};
    gemm64(hrow, oW1t, hi, row16, acc1);
    float h1[4][4];
    #pragma unroll
    for (int n = 0; n < 4; ++n) {
        const float bias = ob1[n * 16 + row16];
        #pragma unroll
        for (int r = 0; r < 4; ++r) {
            h1[n][r] = fmaxf(h0[n][r] + acc1[n][r] + bias, 0.f);
            H_s[w * 16 + hi * 4 + r][n * 16 + row16] = (__bf16)h1[n][r];
        }
    }
    __builtin_amdgcn_wave_barrier();

    f32x4 acc2[4] = {{0,0,0,0},{0,0,0,0},{0,0,0,0},{0,0,0,0}};
    gemm64(hrow, oW2t, hi, row16, acc2);
    #pragma unroll
    for (int n = 0; n < 4; ++n) {
        const float bias = ob2[n * 16 + row16];
        #pragma unroll
        for (int r = 0; r < 4; ++r) {
            const int node = n0 + w * 16 + hi * 4 + r;
            if (node < N_NODES) {
                const int col = n * 16 + row16;
                const float o = h1[n][r] + acc2[n][r] + bias;
                out[(size_t)node * 64 + col] = fmaxf(x[(size_t)node * 64 + col] + o, 0.f);
            }
        }
    }
}

extern "C" void kernel_launch(void* const* d_in, const int* in_sizes, int n_in,
                              void* d_out, int out_size, void* d_ws, size_t ws_size,
                              hipStream_t stream) {
    const float* x  = (const float*)d_in[0];
    const float* ea = (const float*)d_in[1];
    const int*   ei = (const int*)d_in[2];
    const float* q  = (const float*)d_in[3];
    const float* kW0 = (const float*)d_in[4];  const float* kb0 = (const float*)d_in[5];
    const float* kW1 = (const float*)d_in[6];  const float* kb1 = (const float*)d_in[7];
    const float* kW2 = (const float*)d_in[8];  const float* kb2 = (const float*)d_in[9];
    const float* vW0 = (const float*)d_in[10]; const float* vb0 = (const float*)d_in[11];
    const float* vW1 = (const float*)d_in[12]; const float* vb1 = (const float*)d_in[13];
    const float* vW2 = (const float*)d_in[14]; const float* vb2 = (const float*)d_in[15];
    const float* oW0 = (const float*)d_in[16]; const float* ob0 = (const float*)d_in[17];
    const float* oW1 = (const float*)d_in[18]; const float* ob1 = (const float*)d_in[19];
    const float* oW2 = (const float*)d_in[20]; const float* ob2 = (const float*)d_in[21];

    char* ws = (char*)d_ws;
    int*    deg    = (int*)(ws + WS_DEG);
    int*    start  = (int*)(ws + WS_START);
    int*    cursor = (int*)(ws + WS_CURSOR);
    __bf16* wts    = (__bf16*)(ws + WS_WTS);
    int*    perm   = (int*)(ws + WS_PERM);
    __bf16* msg    = (__bf16*)(ws + WS_MSG);
    float*  aggrf  = (float*)d_out;              // d_out doubles as scratch

    __bf16* kW0t = wts;
    __bf16* vW0t = wts + BIG_ELEMS;
    __bf16* sm   = wts + 2 * BIG_ELEMS;
    __bf16* kW1t = sm;                   __bf16* kW2t = sm + SMALL_ELEMS;
    __bf16* vW1t = sm + 2 * SMALL_ELEMS; __bf16* vW2t = sm + 3 * SMALL_ELEMS;
    __bf16* oW0t = sm + 4 * SMALL_ELEMS; __bf16* oW1t = sm + 5 * SMALL_ELEMS;
    __bf16* oW2t = sm + 6 * SMALL_ELEMS;

    hipMemsetAsync(deg, 0, (size_t)N_NODES * sizeof(int), stream);

    // CSR pre-pass (consumed only by aggr_kernel)
    deg_kernel<<<E_EDGES / 256, 256, 0, stream>>>(ei, deg);
    scan_kernel<<<1, 1024, 0, stream>>>(deg, start, cursor);
    perm_kernel<<<E_EDGES / 256, 256, 0, stream>>>(ei, cursor, perm);

    prep_kernel<<<210, 256, 0, stream>>>(kW0, kW1, kW2, vW0, vW1, vW2, oW0, oW1, oW2, wts);

    edge_kernel<<<E_EDGES / 64, 256, 0, stream>>>(
        x, ea, ei, q,
        kb0, kb1, kb2, vb0, vb1, vb2,
        kW0t, kW1t, kW2t, vW0t, vW1t, vW2t,
        msg);

    aggr_kernel<<<(N_NODES + 3) / 4, 256, 0, stream>>>(start, cursor, perm, msg, aggrf);

    node_kernel<<<(N_NODES + 63) / 64, 256, 0, stream>>>(
        x, aggrf, ob0, ob1, ob2, oW0t, oW1t, oW2t, (float*)d_out);
}